// Round 2
// baseline (879.043 us; speedup 1.0000x reference)
//
#include <hip/hip_runtime.h>

#define NN 50000
#define NE 400000
#define D 128
#define KXP 288      // GEMM1 K padded (264 -> 288)
#define KXR 264
#define XSTR 296     // x-tile LDS stride (bf16 elems)
#define MSTR 136     // m-tile LDS stride
#define EPSV 1e-3f

typedef unsigned short u16;
typedef unsigned int u32;
typedef __attribute__((ext_vector_type(4))) float f32x4;
typedef __attribute__((ext_vector_type(8))) short short8;
typedef __attribute__((ext_vector_type(8))) unsigned short ushort8;

__device__ __forceinline__ u16 f2b(float f){
  u32 u = __float_as_uint(f);
  u32 r = u + 0x7fffu + ((u >> 16) & 1u);
  return (u16)(r >> 16);
}
__device__ __forceinline__ float b2f(u16 s){ return __uint_as_float(((u32)s) << 16); }
__device__ __forceinline__ float silu_f(float x){ return x / (1.f + expf(-x)); }

// ---------------- prep: h -> bf16 ----------------
__global__ void k_prep_h(const float* __restrict__ h, u16* __restrict__ hbf){
  int i = blockIdx.x * 256 + threadIdx.x;
  if (i < NN * D) hbf[i] = f2b(h[i]);
}

// ---------------- prep: transposed bf16 weights ----------------
__global__ void k_prep_w(const float* __restrict__ m_w1, const float* __restrict__ m_w2,
                         const float* __restrict__ c_w1, const float* __restrict__ het_w,
                         u16* __restrict__ W1t, u16* __restrict__ W2t,
                         u16* __restrict__ C1t, u16* __restrict__ HtT){
  int i = blockIdx.x * 256 + threadIdx.x;
  if (i < D * KXP){
    int c = i / KXP, k = i - c * KXP;
    W1t[i] = f2b(k < KXR ? m_w1[k * D + c] : 0.f);
    return;
  }
  i -= D * KXP;
  if (i < D * D){ int c = i >> 7, k = i & 127; W2t[i] = f2b(m_w2[k * D + c]); return; }
  i -= D * D;
  if (i < D * D){ int c = i >> 7, k = i & 127; C1t[i] = f2b(c_w1[k * D + c]); return; }
  i -= D * D;
  if (i < D * D){ int c = i >> 7, k = i & 127; HtT[i] = f2b(het_w[k * D + c]); return; }
}

// ---------------- per-node: csum, pooled, ts ----------------
__global__ void k_node_pre(const float* __restrict__ coords, const float* __restrict__ cw,
                           float* __restrict__ pooled, int* __restrict__ tsn){
  int n = blockIdx.x * 256 + threadIdx.x;
  if (n >= NN) return;
  int cs = 0; float px = 0.f, py = 0.f, pz = 0.f;
  #pragma unroll
  for (int c = 0; c < 8; c++){
    float w = cw[n * 8 + c];
    if (w != 0.f){
      cs++;
      px += coords[(size_t)n * 24 + c * 3 + 0];
      py += coords[(size_t)n * 24 + c * 3 + 1];
      pz += coords[(size_t)n * 24 + c * 3 + 2];
    }
  }
  float inv = 1.f / ((float)cs + EPSV);
  pooled[n * 3 + 0] = px * inv;
  pooled[n * 3 + 1] = py * inv;
  pooled[n * 3 + 2] = pz * inv;
  int ts = cs - 1; ts = ts < 0 ? 0 : (ts > 7 ? 7 : ts);
  tsn[n] = ts;
}

// ---------------- edge pass A: global max sq-norm + in-degree ----------------
__global__ __launch_bounds__(256) void k_edge_max(const float* __restrict__ coords,
                                                  const int* __restrict__ el,
                                                  u32* __restrict__ maxsq, u32* __restrict__ cnt){
  int e = blockIdx.x * 256 + threadIdx.x;
  float vm = 0.f;
  if (e < NE){
    int s = el[e * 3 + 0], t = el[e * 3 + 1];
    float ct[24], cs_[24];
    #pragma unroll
    for (int i = 0; i < 24; i++) ct[i] = coords[(size_t)t * 24 + i];
    #pragma unroll
    for (int i = 0; i < 24; i++) cs_[i] = coords[(size_t)s * 24 + i];
    #pragma unroll
    for (int c1 = 0; c1 < 8; c1++){
      #pragma unroll
      for (int c2 = 0; c2 < 8; c2++){
        float dx = ct[c1 * 3 + 0] - cs_[c2 * 3 + 0];
        float dy = ct[c1 * 3 + 1] - cs_[c2 * 3 + 1];
        float dz = ct[c1 * 3 + 2] - cs_[c2 * 3 + 2];
        vm = fmaxf(vm, dx * dx + dy * dy + dz * dz);
      }
    }
    atomicAdd(&cnt[t], 1u);
  }
  __shared__ float red[256];
  red[threadIdx.x] = vm;
  __syncthreads();
  for (int s2 = 128; s2 > 0; s2 >>= 1){
    if (threadIdx.x < s2) red[threadIdx.x] = fmaxf(red[threadIdx.x], red[threadIdx.x + s2]);
    __syncthreads();
  }
  if (threadIdx.x == 0) atomicMax(maxsq, __float_as_uint(red[0]));
}

// ---------------- radial features (4 threads / edge) ----------------
__global__ __launch_bounds__(256) void k_radial(const float* __restrict__ coords,
                                                const float* __restrict__ attr,
                                                const float* __restrict__ cw,
                                                const int* __restrict__ el,
                                                const float* __restrict__ rl_w,
                                                const float* __restrict__ rl_b,
                                                const u32* __restrict__ maxsq,
                                                float* __restrict__ radial8){
  __shared__ float sct[64][24], scs[64][24], sAs[64][64], scwt[64][8], scws[64][8], stmp[64][64];
  const int tid = threadIdx.x;
  const int er = tid >> 2;
  const int q = tid & 3;
  const int e = blockIdx.x * 64 + er;
  const int s = el[e * 3 + 0];
  const int t = el[e * 3 + 1];

  #pragma unroll
  for (int i = 0; i < 6; i++) sct[er][q * 6 + i] = coords[(size_t)t * 24 + q * 6 + i];
  #pragma unroll
  for (int i = 0; i < 6; i++) scs[er][q * 6 + i] = coords[(size_t)s * 24 + q * 6 + i];
  #pragma unroll
  for (int i = 0; i < 16; i++) sAs[er][q * 16 + i] = attr[(size_t)s * 64 + q * 16 + i];
  #pragma unroll
  for (int i = 0; i < 2; i++){
    scwt[er][q * 2 + i] = cw[(size_t)t * 8 + q * 2 + i];
    scws[er][q * 2 + i] = cw[(size_t)s * 8 + q * 2 + i];
  }
  __syncthreads();

  const float scale = 1.f / (sqrtf(__uint_as_float(*maxsq)) + EPSV);

  // tmp[c][b] = sum_d msg[c][d] * As[d][b]   (this thread: c = 2q, 2q+1)
  float tmp[2][8];
  #pragma unroll
  for (int ci = 0; ci < 2; ci++)
    #pragma unroll
    for (int b = 0; b < 8; b++) tmp[ci][b] = 0.f;
  #pragma unroll
  for (int d = 0; d < 8; d++){
    float as[8];
    #pragma unroll
    for (int b = 0; b < 8; b++) as[b] = sAs[er][d * 8 + b];
    #pragma unroll
    for (int ci = 0; ci < 2; ci++){
      int c = q * 2 + ci;
      float dx = sct[er][c * 3 + 0] - scs[er][d * 3 + 0];
      float dy = sct[er][c * 3 + 1] - scs[er][d * 3 + 1];
      float dz = sct[er][c * 3 + 2] - scs[er][d * 3 + 2];
      float msg = sqrtf(dx * dx + dy * dy + dz * dz) * scale * scwt[er][c] * scws[er][d];
      #pragma unroll
      for (int b = 0; b < 8; b++) tmp[ci][b] += msg * as[b];
    }
  }
  #pragma unroll
  for (int ci = 0; ci < 2; ci++)
    #pragma unroll
    for (int b = 0; b < 8; b++) stmp[er][(q * 2 + ci) * 8 + b] = tmp[ci][b];
  __syncthreads();

  // radial[a][b] = sum_c At[c][a] * tmp[c][b]   (this thread: a = 2q, 2q+1)
  float rad[2][8];
  #pragma unroll
  for (int ai = 0; ai < 2; ai++)
    #pragma unroll
    for (int b = 0; b < 8; b++) rad[ai][b] = 0.f;
  #pragma unroll
  for (int c = 0; c < 8; c++){
    float at0 = attr[(size_t)t * 64 + c * 8 + 2 * q + 0];
    float at1 = attr[(size_t)t * 64 + c * 8 + 2 * q + 1];
    #pragma unroll
    for (int b = 0; b < 8; b++){
      float tv = stmp[er][c * 8 + b];
      rad[0][b] += at0 * tv;
      rad[1][b] += at1 * tv;
    }
  }
  float sq = 0.f;
  #pragma unroll
  for (int ai = 0; ai < 2; ai++)
    #pragma unroll
    for (int b = 0; b < 8; b++) sq += rad[ai][b] * rad[ai][b];
  sq += __shfl_xor(sq, 1);
  sq += __shfl_xor(sq, 2);
  const float rn = 1.f / (sqrtf(sq) + EPSV);

  float o[8];
  #pragma unroll
  for (int j = 0; j < 8; j++) o[j] = 0.f;
  #pragma unroll
  for (int ai = 0; ai < 2; ai++){
    int a = 2 * q + ai;
    #pragma unroll
    for (int b = 0; b < 8; b++){
      float v = rad[ai][b] * rn;
      int row = a * 8 + b;
      #pragma unroll
      for (int j = 0; j < 8; j++) o[j] += v * rl_w[row * 8 + j];
    }
  }
  #pragma unroll
  for (int j = 0; j < 8; j++){
    o[j] += __shfl_xor(o[j], 1);
    o[j] += __shfl_xor(o[j], 2);
  }
  if (q == 0){
    #pragma unroll
    for (int j = 0; j < 8; j++) radial8[(size_t)e * 8 + j] = o[j] + rl_b[j];
  }
}

// ---------------- fused edge MLP + aggregation ----------------
__global__ __launch_bounds__(256, 2) void k_edge_mlp(
    const int* __restrict__ el, const float* __restrict__ ewg,
    const float* __restrict__ radial8, const u16* __restrict__ hbf,
    const u16* __restrict__ W1t, const u16* __restrict__ W2t, const u16* __restrict__ C1t,
    const float* __restrict__ m_b1, const float* __restrict__ m_b2,
    const float* __restrict__ c_b1, const float* __restrict__ c_w2,
    const float* __restrict__ coords, const float* __restrict__ pooled,
    const int* __restrict__ tsn, const float* __restrict__ w_r,
    float* __restrict__ out_node, float* __restrict__ out_coord)
{
  __shared__ u16 sx[64 * XSTR];   // x tile / later ef1 tile
  __shared__ u16 sm[64 * MSTR];   // m1 tile / later m tile (in-place, wave-local)
  __shared__ float sef[64 * 8];
  __shared__ int s_tgt[64];
  __shared__ int s_src[64];
  __shared__ float s_ew[64];

  const int tid = threadIdx.x;
  const int lane = tid & 63;
  const int wv = tid >> 6;          // wave 0..3, owns rows [16*wv, 16*wv+16)
  const int wrow = wv * 16;
  const int e0 = blockIdx.x * 64;
  const int lc = lane & 15;
  const int lk = (lane >> 4) * 8;
  const f32x4 zero = {0.f, 0.f, 0.f, 0.f};

  // ---- fill x tile (wave-local rows) ----
  {
    const int er = wrow + (lane >> 2);
    const int q = lane & 3;
    const int e = e0 + er;
    const int s = el[e * 3 + 0];
    const int t = el[e * 3 + 1];
    if (q == 0){ s_src[er] = s; s_tgt[er] = t; s_ew[er] = ewg[e]; }
    const u16* srow = (q < 2) ? (hbf + (size_t)t * D + q * 64)
                              : (hbf + (size_t)s * D + (q - 2) * 64);
    const int colbase = (q < 2) ? (q * 64) : (128 + (q - 2) * 64);
    u16* dst = sx + er * XSTR + colbase;
    #pragma unroll
    for (int i = 0; i < 8; i++)
      *(ushort8*)(dst + i * 8) = *(const ushort8*)(srow + i * 8);
    if (q == 0){
      #pragma unroll
      for (int j = 0; j < 8; j++) sx[er * XSTR + 256 + j] = f2b(radial8[(size_t)e * 8 + j]);
      #pragma unroll
      for (int j = 264; j < 288; j++) sx[er * XSTR + j] = 0;
    }
  }
  __syncthreads();

  f32x4 acc[8];

  // ---- GEMM1: m1 = silu(x @ W1 + b1) ----
  #pragma unroll
  for (int nb = 0; nb < 8; nb++) acc[nb] = zero;
  #pragma unroll
  for (int kb = 0; kb < 9; kb++){
    short8 a = *(const short8*)(sx + (wrow + lc) * XSTR + kb * 32 + lk);
    #pragma unroll
    for (int nb = 0; nb < 8; nb++){
      short8 b = *(const short8*)(W1t + (size_t)(nb * 16 + lc) * KXP + kb * 32 + lk);
      acc[nb] = __builtin_amdgcn_mfma_f32_16x16x32_bf16(a, b, acc[nb], 0, 0, 0);
    }
  }
  #pragma unroll
  for (int nb = 0; nb < 8; nb++){
    const int col = nb * 16 + lc;
    const float bias = m_b1[col];
    #pragma unroll
    for (int j = 0; j < 4; j++){
      const int row = wrow + (lane >> 4) * 4 + j;
      sm[row * MSTR + col] = f2b(silu_f(acc[nb][j] + bias));
    }
  }

  // ---- GEMM2: m = silu(m1 @ W2 + b2); node_agg atomics ----
  #pragma unroll
  for (int nb = 0; nb < 8; nb++) acc[nb] = zero;
  #pragma unroll
  for (int kb = 0; kb < 4; kb++){
    short8 a = *(const short8*)(sm + (wrow + lc) * MSTR + kb * 32 + lk);
    #pragma unroll
    for (int nb = 0; nb < 8; nb++){
      short8 b = *(const short8*)(W2t + (size_t)(nb * 16 + lc) * D + kb * 32 + lk);
      acc[nb] = __builtin_amdgcn_mfma_f32_16x16x32_bf16(a, b, acc[nb], 0, 0, 0);
    }
  }
  #pragma unroll
  for (int nb = 0; nb < 8; nb++){
    const int col = nb * 16 + lc;
    const float bias = m_b2[col];
    #pragma unroll
    for (int j = 0; j < 4; j++){
      const int row = wrow + (lane >> 4) * 4 + j;
      const float v = silu_f(acc[nb][j] + bias);
      atomicAdd(&out_node[(size_t)s_tgt[row] * D + col], v * s_ew[row]);
      sm[row * MSTR + col] = f2b(v);
    }
  }

  // ---- GEMM3: ef1 = silu(m @ c_w1 + c_b1) -> sx (scratch) ----
  #pragma unroll
  for (int nb = 0; nb < 8; nb++) acc[nb] = zero;
  #pragma unroll
  for (int kb = 0; kb < 4; kb++){
    short8 a = *(const short8*)(sm + (wrow + lc) * MSTR + kb * 32 + lk);
    #pragma unroll
    for (int nb = 0; nb < 8; nb++){
      short8 b = *(const short8*)(C1t + (size_t)(nb * 16 + lc) * D + kb * 32 + lk);
      acc[nb] = __builtin_amdgcn_mfma_f32_16x16x32_bf16(a, b, acc[nb], 0, 0, 0);
    }
  }
  #pragma unroll
  for (int nb = 0; nb < 8; nb++){
    const int col = nb * 16 + lc;
    const float bias = c_b1[col];
    #pragma unroll
    for (int j = 0; j < 4; j++){
      const int row = wrow + (lane >> 4) * 4 + j;
      sx[row * XSTR + col] = f2b(silu_f(acc[nb][j] + bias));
    }
  }

  // ---- GEMM4 (VALU): edge_feat = ef1 @ c_w2 ----
  {
    const int r0 = wrow + (lane >> 3);
    const int c8 = lane & 7;
    float a0 = 0.f, a1 = 0.f;
    #pragma unroll
    for (int kk = 0; kk < 128; kk += 8){
      ushort8 v0 = *(const ushort8*)(sx + r0 * XSTR + kk);
      ushort8 v1 = *(const ushort8*)(sx + (r0 + 8) * XSTR + kk);
      #pragma unroll
      for (int j = 0; j < 8; j++){
        const float wv2 = c_w2[(kk + j) * 8 + c8];
        a0 += b2f((u16)v0[j]) * wv2;
        a1 += b2f((u16)v1[j]) * wv2;
      }
    }
    sef[r0 * 8 + c8] = a0;
    sef[(r0 + 8) * 8 + c8] = a1;
  }

  // ---- coord message + scatter ----
  {
    const int er = wrow + (lane >> 2);
    const int q = lane & 3;                 // channels 2q, 2q+1
    const int t = s_tgt[er], s = s_src[er];
    const int ts = tsn[t];
    const int w8 = 8 - ts;
    const float invw = 1.f / (float)w8;
    const float wr0 = w_r[0];
    const float p0 = pooled[s * 3 + 0], p1 = pooled[s * 3 + 1], p2 = pooled[s * 3 + 2];
    #pragma unroll
    for (int ci = 0; ci < 2; ci++){
      const int c = q * 2 + ci;
      float pe = 0.f;
      const int hi = (c + w8 < 8) ? (c + w8) : 8;
      for (int j = c; j < hi; j++) pe += sef[er * 8 + j];
      pe *= invw * wr0;
      const size_t ob = (size_t)t * 24 + c * 3;
      atomicAdd(&out_coord[ob + 0], (coords[(size_t)t * 24 + c * 3 + 0] - p0) * pe);
      atomicAdd(&out_coord[ob + 1], (coords[(size_t)t * 24 + c * 3 + 1] - p1) * pe);
      atomicAdd(&out_coord[ob + 2], (coords[(size_t)t * 24 + c * 3 + 2] - p2) * pe);
    }
  }
}

// ---------------- final: het GEMM + BN + silu + residual; coord finalize ----------------
__global__ __launch_bounds__(256) void k_final(
    const float* __restrict__ h, const float* __restrict__ coords,
    const u16* __restrict__ HtT, const float* __restrict__ het_b,
    const float* __restrict__ bn_g, const float* __restrict__ bn_b,
    const u32* __restrict__ cnt, float* __restrict__ dout)
{
  __shared__ u16 sa[64 * MSTR];
  const int tid = threadIdx.x, lane = tid & 63, wv = tid >> 6, wrow = wv * 16;
  const int nb0 = blockIdx.x * 64;
  float* out_node = dout;
  float* out_coord = dout + (size_t)NN * D;
  const int lc = lane & 15, lk = (lane >> 4) * 8;
  const f32x4 zero = {0.f, 0.f, 0.f, 0.f};

  // stage agg rows (wave-local, bf16)
  #pragma unroll
  for (int i = 0; i < 32; i++){
    const int idx = i * 64 + lane;
    const int r = idx >> 7, c = idx & 127;
    sa[(wrow + r) * MSTR + c] = f2b(out_node[(size_t)(nb0 + wrow + r) * D + c]);
  }

  f32x4 acc[8];
  #pragma unroll
  for (int nb = 0; nb < 8; nb++) acc[nb] = zero;
  #pragma unroll
  for (int kb = 0; kb < 4; kb++){
    short8 a = *(const short8*)(sa + (wrow + lc) * MSTR + kb * 32 + lk);
    #pragma unroll
    for (int nb = 0; nb < 8; nb++){
      short8 b = *(const short8*)(HtT + (size_t)(nb * 16 + lc) * D + kb * 32 + lk);
      acc[nb] = __builtin_amdgcn_mfma_f32_16x16x32_bf16(a, b, acc[nb], 0, 0, 0);
    }
  }
  const float invs = rsqrtf(1.f + 1e-5f);
  #pragma unroll
  for (int nb = 0; nb < 8; nb++){
    const int col = nb * 16 + lc;
    const float hb = het_b[col], g = bn_g[col], be = bn_b[col];
    #pragma unroll
    for (int j = 0; j < 4; j++){
      const int row = wrow + (lane >> 4) * 4 + j;
      const int node = nb0 + row;
      if (node < NN){
        float v = silu_f((acc[nb][j] + hb) * invs * g + be);
        out_node[(size_t)node * D + col] = v + h[(size_t)node * D + col];
      }
    }
  }
  // coord finalize
  #pragma unroll
  for (int i = 0; i < 6; i++){
    const int idx = i * 256 + tid;
    const int nl = idx / 24, rem = idx - nl * 24;
    const int node = nb0 + nl;
    if (node < NN){
      const size_t o = (size_t)node * 24 + rem;
      const u32 cn = cnt[node];
      const float cv = (float)(cn > 0u ? cn : 1u);
      out_coord[o] = coords[o] + out_coord[o] / cv;
    }
  }
}

extern "C" void kernel_launch(void* const* d_in, const int* in_sizes, int n_in,
                              void* d_out, int out_size, void* d_ws, size_t ws_size,
                              hipStream_t stream)
{
  const float* h      = (const float*)d_in[0];
  const float* coords = (const float*)d_in[1];
  const float* cattr  = (const float*)d_in[2];
  const float* cw     = (const float*)d_in[3];
  const float* ewg    = (const float*)d_in[4];
  const int*   el     = (const int*)  d_in[5];
  const float* rl_w   = (const float*)d_in[6];
  const float* rl_b   = (const float*)d_in[7];
  const float* m_w1   = (const float*)d_in[8];
  const float* m_b1   = (const float*)d_in[9];
  const float* m_w2   = (const float*)d_in[10];
  const float* m_b2   = (const float*)d_in[11];
  const float* c_w1   = (const float*)d_in[12];
  const float* c_b1   = (const float*)d_in[13];
  const float* c_w2   = (const float*)d_in[14];
  const float* het_w  = (const float*)d_in[15];
  const float* het_b  = (const float*)d_in[16];
  const float* bn_g   = (const float*)d_in[17];
  const float* bn_b   = (const float*)d_in[18];
  const float* w_r    = (const float*)d_in[19];

  char* wsb = (char*)d_ws;
  size_t off = 0;
  auto take = [&](size_t bytes)->char*{
    char* p = wsb + off;
    off = (off + bytes + 255) & ~(size_t)255;
    return p;
  };
  u32*   maxsq  = (u32*)  take(4);
  float* pooled = (float*)take((size_t)NN * 3 * 4);
  int*   tsn    = (int*)  take((size_t)NN * 4);
  u32*   cnt    = (u32*)  take((size_t)NN * 4);
  float* rad8   = (float*)take((size_t)NE * 8 * 4);
  u16*   hbf    = (u16*)  take((size_t)NN * D * 2);
  u16*   W1t    = (u16*)  take((size_t)D * KXP * 2);
  u16*   W2t    = (u16*)  take((size_t)D * D * 2);
  u16*   C1t    = (u16*)  take((size_t)D * D * 2);
  u16*   HtT    = (u16*)  take((size_t)D * D * 2);

  float* out_node  = (float*)d_out;
  float* out_coord = out_node + (size_t)NN * D;

  hipMemsetAsync(d_out, 0, (size_t)out_size * sizeof(float), stream);
  hipMemsetAsync(maxsq, 0, 4, stream);
  hipMemsetAsync(cnt, 0, (size_t)NN * 4, stream);

  k_prep_h  <<<dim3((NN * D) / 256), dim3(256), 0, stream>>>(h, hbf);
  k_prep_w  <<<dim3((D * KXP + 3 * D * D) / 256), dim3(256), 0, stream>>>(m_w1, m_w2, c_w1, het_w, W1t, W2t, C1t, HtT);
  k_node_pre<<<dim3((NN + 255) / 256), dim3(256), 0, stream>>>(coords, cw, pooled, tsn);
  k_edge_max<<<dim3((NE + 255) / 256), dim3(256), 0, stream>>>(coords, el, maxsq, cnt);
  k_radial  <<<dim3(NE / 64), dim3(256), 0, stream>>>(coords, cattr, cw, el, rl_w, rl_b, maxsq, rad8);
  k_edge_mlp<<<dim3(NE / 64), dim3(256), 0, stream>>>(el, ewg, rad8, hbf, W1t, W2t, C1t,
        m_b1, m_b2, c_b1, c_w2, coords, pooled, tsn, w_r, out_node, out_coord);
  k_final   <<<dim3((NN + 63) / 64), dim3(256), 0, stream>>>(h, coords, HtT, het_b, bn_g, bn_b, cnt, (float*)d_out);
}